// Round 2
// baseline (372.127 us; speedup 1.0000x reference)
//
#include <hip/hip_runtime.h>
#include <math.h>

// Problem constants: B=128, S=4096, D_IN=128, E=1, D_OUT=64, DELAY=2
#define S_LEN   4096
#define BATCH   128
#define DIN     128
#define DELAY_N 2
#define NDIFF   (S_LEN - DELAY_N)      // 4094
#define SCHUNK  256
#define NCHUNK  (S_LEN / SCHUNK)       // 16
#define NBLK    (BATCH * NCHUNK)       // 2048

// Main streaming kernel: block = (batch b, s-chunk). Lane layout: 16 lanes per
// row (each lane owns 8 columns = 32B), 4 rows per wave per group. Reduction
// over 16 lanes via xor masks 8/4/2/1 (stay in-group). Loads: 2x dwordx4/lane,
// a wave covers 2 KiB contiguous per group.
__global__ __launch_bounds__(256)
void mle_main(const float* __restrict__ x,
              const float* __restrict__ w1,
              const float* __restrict__ b1,
              const float* __restrict__ w2,
              const float* __restrict__ b2,
              double* __restrict__ partials) {
  const int blk     = blockIdx.x;
  const int b       = blk / NCHUNK;
  const int s0      = (blk % NCHUNK) * SCHUNK;
  const int tid     = threadIdx.x;
  const int lane    = tid & 63;
  const int wave    = tid >> 6;            // 4 waves/block
  const int quarter = lane >> 4;           // which of 4 rows in the group
  const int l16     = lane & 15;           // 16 lanes per row
  const int col     = l16 * 8;             // 8 columns per lane

  __shared__ float  tbuf[SCHUNK + DELAY_N];
  __shared__ double wpart[8];

  // Per-lane slices of the two w1 rows (8 columns each).
  const float4 wa0 = *(const float4*)(w1 + col);
  const float4 wa1 = *(const float4*)(w1 + col + 4);
  const float4 wb0 = *(const float4*)(w1 + DIN + col);
  const float4 wb1 = *(const float4*)(w1 + DIN + col + 4);
  const float b1a = b1[0], b1b = b1[1];
  const float w2a = w2[0], w2b = w2[1], b20 = b2[0];

  // Rows of t this block computes: SCHUNK+2 (256 for the last chunk).
  const int R = min(SCHUNK + DELAY_N, S_LEN - s0);
  const int G = (R + 3) >> 2;              // groups of 4 rows
  const float* xb = x + ((size_t)b * S_LEN + (size_t)s0) * DIN;

  constexpr int U = 4;
  for (int g0 = wave; g0 < G; g0 += 4 * U) {
    float4 v0[U], v1[U];
    #pragma unroll
    for (int u = 0; u < U; ++u) {
      const int g = g0 + 4 * u;
      if (g < G) {                          // wave-uniform
        const int row = min(4 * g + quarter, R - 1);  // clamp partial tail group
        const float* p = xb + (size_t)row * DIN + col;
        v0[u] = *(const float4*)(p);
        v1[u] = *(const float4*)(p + 4);
      }
    }
    #pragma unroll
    for (int u = 0; u < U; ++u) {
      const int g = g0 + 4 * u;
      if (g >= G) continue;
      float d0 = v0[u].x * wa0.x + v0[u].y * wa0.y + v0[u].z * wa0.z + v0[u].w * wa0.w
               + v1[u].x * wa1.x + v1[u].y * wa1.y + v1[u].z * wa1.z + v1[u].w * wa1.w;
      float d1 = v0[u].x * wb0.x + v0[u].y * wb0.y + v0[u].z * wb0.z + v0[u].w * wb0.w
               + v1[u].x * wb1.x + v1[u].y * wb1.y + v1[u].z * wb1.z + v1[u].w * wb1.w;
      #pragma unroll
      for (int m = 8; m >= 1; m >>= 1) {    // stays within the 16-lane group
        d0 += __shfl_xor(d0, m);
        d1 += __shfl_xor(d1, m);
      }
      if (l16 == 0) {
        const int row = 4 * g + quarter;
        if (row < R) {
          tbuf[row] = w2a * fmaxf(d0 + b1a, 0.0f)
                    + w2b * fmaxf(d1 + b1b, 0.0f) + b20;
        }
      }
    }
  }
  __syncthreads();

  // Partial sums of log|t[s+2]-t[s]| and its square over this chunk.
  double ls = 0.0, ls2 = 0.0;
  const int nd = min(SCHUNK, NDIFF - s0);   // 256 (254 for the last chunk)
  for (int i = tid; i < nd; i += 256) {
    const float d  = fabsf(tbuf[i + DELAY_N] - tbuf[i]);
    const float ld = logf(d + 1e-6f);
    ls  += (double)ld;
    ls2 += (double)ld * (double)ld;
  }
  #pragma unroll
  for (int m = 32; m >= 1; m >>= 1) {
    ls  += __shfl_xor(ls, m);
    ls2 += __shfl_xor(ls2, m);
  }
  if (lane == 0) { wpart[wave * 2] = ls; wpart[wave * 2 + 1] = ls2; }
  __syncthreads();
  if (tid == 0) {
    partials[blk * 2 + 0] = wpart[0] + wpart[2] + wpart[4] + wpart[6];
    partials[blk * 2 + 1] = wpart[1] + wpart[3] + wpart[5] + wpart[7];
  }
}

// Finalize: per batch, fold NCHUNK partials, mean/std (ddof=1),
// out[b, j] = tanh(mean*w3[j,0] + std*w3[j,1] + b3[j]), broadcast (64,64).
__global__ __launch_bounds__(256)
void mle_final(const double* __restrict__ partials,
               const float* __restrict__ w3,
               const float* __restrict__ b3,
               float* __restrict__ out) {
  const int b   = blockIdx.x;
  const int tid = threadIdx.x;

  double sum = 0.0, sumsq = 0.0;
  #pragma unroll
  for (int c = 0; c < NCHUNK; ++c) {
    sum   += partials[(b * NCHUNK + c) * 2 + 0];
    sumsq += partials[(b * NCHUNK + c) * 2 + 1];
  }
  const double n    = (double)NDIFF;
  const double mean = sum / n;
  double var = (sumsq - n * mean * mean) / (n - 1.0);
  if (var < 0.0) var = 0.0;
  const float meanf = (float)mean;
  const float stdf  = (float)sqrt(var);

  __shared__ float vals[64];
  if (tid < 64) {
    vals[tid] = tanhf(meanf * w3[tid * 2] + stdf * w3[tid * 2 + 1] + b3[tid]);
  }
  __syncthreads();

  const int j = (4 * tid) & 63;
  const float4 v = make_float4(vals[j], vals[j + 1], vals[j + 2], vals[j + 3]);
  float4* o = (float4*)(out + (size_t)b * (64 * 64));
  #pragma unroll
  for (int k = 0; k < 4; ++k) {
    o[tid + k * 256] = v;
  }
}

extern "C" void kernel_launch(void* const* d_in, const int* in_sizes, int n_in,
                              void* d_out, int out_size, void* d_ws, size_t ws_size,
                              hipStream_t stream) {
  const float* x  = (const float*)d_in[0];
  const float* w1 = (const float*)d_in[1];
  const float* b1 = (const float*)d_in[2];
  const float* w2 = (const float*)d_in[3];
  const float* b2 = (const float*)d_in[4];
  const float* w3 = (const float*)d_in[5];
  const float* b3 = (const float*)d_in[6];
  float* out = (float*)d_out;

  double* partials = (double*)d_ws;   // NBLK * 2 doubles = 32 KiB

  mle_main <<<NBLK,  256, 0, stream>>>(x, w1, b1, w2, b2, partials);
  mle_final<<<BATCH, 256, 0, stream>>>(partials, w3, b3, out);
}